// Round 17
// baseline (273.381 us; speedup 1.0000x reference)
//
#include <hip/hip_runtime.h>

typedef __bf16 bf16;
typedef __bf16 bf16x8 __attribute__((ext_vector_type(8)));
typedef __bf16 bf16x4 __attribute__((ext_vector_type(4)));
typedef float f32x4 __attribute__((ext_vector_type(4)));
typedef float f32x16 __attribute__((ext_vector_type(16)));
typedef unsigned u32x4 __attribute__((ext_vector_type(4)));

#define EXP2F(x) __builtin_amdgcn_exp2f(x)

#define LOAD_LDS16(gp, lp)                                                     \
  __builtin_amdgcn_global_load_lds(                                            \
      (const __attribute__((address_space(1))) void*)(gp),                     \
      (__attribute__((address_space(3))) void*)(lp), 16, 0, 0)

// ---- merged pre-pass: x f32->bf16 cvt + Wqkv/Wproj transpose to [N][K] ----
__global__ __launch_bounds__(256) void k_pre(const float* __restrict__ x,
                                             const float* __restrict__ Wqkv,
                                             const float* __restrict__ Wproj,
                                             bf16* __restrict__ xb,
                                             bf16* __restrict__ Wqkvt,
                                             bf16* __restrict__ Wprojt) {
  int bid = blockIdx.x, tid = threadIdx.x;
  if (bid < 8192) {
    int i = bid * 256 + tid;
    float4 v = ((const float4*)x)[i];
    bf16x4 o = {(bf16)v.x, (bf16)v.y, (bf16)v.z, (bf16)v.w};
    ((bf16x4*)xb)[i] = o;
    return;
  }
  __shared__ bf16 t[64 * 65];
  const float* in;
  bf16* out;
  int R, C, c0, r0;
  if (bid < 9728) {
    int f = bid - 8192;
    in = Wqkv; out = Wqkvt; R = 2048; C = 3072;
    c0 = (f % 48) * 64; r0 = (f / 48) * 64;
  } else {
    int f = bid - 9728;
    in = Wproj; out = Wprojt; R = 2048; C = 2048;
    c0 = (f & 31) * 64; r0 = (f >> 5) * 64;
  }
#pragma unroll
  for (int i = 0; i < 16; ++i) {
    int f = i * 256 + tid;
    int rl = f >> 6, cl = f & 63;
    t[rl * 65 + cl] = (bf16)in[(size_t)(r0 + rl) * C + c0 + cl];
  }
  __syncthreads();
#pragma unroll
  for (int i = 0; i < 16; ++i) {
    int f = i * 256 + tid;
    int cl = f >> 6, rl = f & 63;
    out[(size_t)(c0 + cl) * R + r0 + rl] = t[rl * 65 + cl];
  }
}

// ---- bf16 GEMM, BMx256 tile ----
// BM=256: DEEP-PREFETCH variant — both kh halves of T+1 issued at p0/p1;
// vmcnt(8)@p1 certifies kh1(T) (4-phase cover), vmcnt(4)@p3 certifies
// kh0(T+1) (3-phase cover). FIFO verified for prologue/steady/last tile;
// every LDS half's last reader completes >=2 barriers before overwrite issue.
// BM=128 (proj): round-7/11/15-validated schedule, unchanged.
template <typename OutT, int BM>
__global__ __launch_bounds__(512, 2) void k_gemm256(const bf16* __restrict__ A,
                                                    const bf16* __restrict__ Bt,
                                                    OutT* __restrict__ C,
                                                    int M, int N, int K) {
  constexpr int ASZ = 4 * BM * 8;
  constexpr int MREP = BM / 32;
  __shared__ alignas(16) bf16 As[2][2][ASZ];
  __shared__ alignas(16) bf16 Bs[2][2][4 * 256 * 8];
  int tid = threadIdx.x;
  int wid = tid >> 6, lane = tid & 63;
  int g = lane >> 4, lr = lane & 15;
  int wrow = (wid >> 2) * (BM / 2), wcol = (wid & 3) * 64;
  int gx = gridDim.x;
  int flat = blockIdx.y * gx + blockIdx.x;
  int cpx = (gx * gridDim.y) >> 3;
  int f2 = (flat & 7) * cpx + (flat >> 3);
  int row0 = (f2 % gx) * BM, col0 = (f2 / gx) * 256;
  int NT = K >> 6;
  f32x4 acc[MREP][4] = {};

  auto stageA = [&](int buf, int kh, int kt) {
#pragma unroll
    for (int pass = 0; pass < BM / 128; ++pass) {
      int slot = pass * 512 + tid;
      int kseg, row;
      if constexpr (BM == 256) { kseg = slot >> 8; row = slot & 255; }
      else { kseg = slot >> 7; row = slot & 127; }
      LOAD_LDS16(A + (size_t)(row0 + row) * K + kt * 64 + kh * 32 + kseg * 8,
                 &As[buf][kh][slot * 8]);
    }
  };
  auto stageB = [&](int buf, int kh, int kt) {
#pragma unroll
    for (int pass = 0; pass < 2; ++pass) {
      int slot = pass * 512 + tid;
      int kseg = slot >> 8, row = slot & 255;
      LOAD_LDS16(Bt + (size_t)(col0 + row) * K + kt * 64 + kh * 32 + kseg * 8,
                 &Bs[buf][kh][slot * 8]);
    }
  };
  auto dsA = [&](int buf, int s, int mq, bf16x8* af) {
#pragma unroll
    for (int i = 0; i < 4; ++i)
      af[i] = *(const bf16x8*)&As[buf][s]
                  [(g * BM + wrow + (mq * 4 + i) * 16 + lr) * 8];
  };
  auto dsB = [&](int buf, int s, bf16x8* bfr) {
#pragma unroll
    for (int i = 0; i < 4; ++i)
      bfr[i] = *(const bf16x8*)&Bs[buf][s][((g << 8) + wcol + i * 16 + lr) * 8];
  };
  auto mfma16 = [&](int mq, bf16x8* af, bf16x8* bfr) {
    __builtin_amdgcn_s_setprio(1);
#pragma unroll
    for (int i = 0; i < 4; ++i)
#pragma unroll
      for (int n = 0; n < 4; ++n)
        acc[mq * 4 + i][n] = __builtin_amdgcn_mfma_f32_16x16x32_bf16(
            af[i], bfr[n], acc[mq * 4 + i][n], 0, 0, 0);
    __builtin_amdgcn_s_setprio(0);
  };

  stageA(0, 0, 0);
  stageB(0, 0, 0);
  stageA(0, 1, 0);
  stageB(0, 1, 0);
  if constexpr (BM == 256)
    asm volatile("s_waitcnt vmcnt(4)" ::: "memory");
  else
    asm volatile("s_waitcnt vmcnt(3)" ::: "memory");
  __builtin_amdgcn_s_barrier();

  for (int T = 0; T < NT; ++T) {
    int buf = T & 1, nbuf = buf ^ 1;
    bool more = (T + 1 < NT);
    bf16x8 af[4], bfr[4];
    if constexpr (BM == 256) {
      // ---- p0: kh0, mq0 ---- (issue kh0(T+1))
      dsA(buf, 0, 0, af);
      dsB(buf, 0, bfr);
      if (more) { stageA(nbuf, 0, T + 1); stageB(nbuf, 0, T + 1); }
      __builtin_amdgcn_s_barrier();
      mfma16(0, af, bfr);
      __builtin_amdgcn_s_barrier();
      // ---- p1: kh0, mq1 ---- (issue kh1(T+1); certify kh1(T))
      dsA(buf, 0, 1, af);
      if (more) {
        stageA(nbuf, 1, T + 1);
        stageB(nbuf, 1, T + 1);
        asm volatile("s_waitcnt vmcnt(8)" ::: "memory");  // kh1(T) landed
      } else {
        asm volatile("s_waitcnt vmcnt(0)" ::: "memory");
      }
      __builtin_amdgcn_s_barrier();
      mfma16(1, af, bfr);
      __builtin_amdgcn_s_barrier();
      // ---- p2: kh1, mq0 ----
      dsA(buf, 1, 0, af);
      dsB(buf, 1, bfr);
      __builtin_amdgcn_s_barrier();
      mfma16(0, af, bfr);
      __builtin_amdgcn_s_barrier();
      // ---- p3: kh1, mq1 ---- (certify kh0(T+1))
      dsA(buf, 1, 1, af);
      if (more)
        asm volatile("s_waitcnt vmcnt(4)" ::: "memory");  // kh0(T+1) landed
      __builtin_amdgcn_s_barrier();
      mfma16(1, af, bfr);
      __builtin_amdgcn_s_barrier();
    } else {
      dsA(buf, 0, 0, af);
      dsB(buf, 0, bfr);
      if (more) {
        stageA(nbuf, 0, T + 1);
        stageB(nbuf, 0, T + 1);
        asm volatile("s_waitcnt vmcnt(3)" ::: "memory");
      } else {
        asm volatile("s_waitcnt vmcnt(0)" ::: "memory");
      }
      __builtin_amdgcn_s_barrier();
      mfma16(0, af, bfr);
      __builtin_amdgcn_s_barrier();
      dsA(buf, 1, 0, af);
      dsB(buf, 1, bfr);
      if (more) {
        stageA(nbuf, 1, T + 1);
        stageB(nbuf, 1, T + 1);
        asm volatile("s_waitcnt vmcnt(3)" ::: "memory");
      }
      __builtin_amdgcn_s_barrier();
      mfma16(0, af, bfr);
      __builtin_amdgcn_s_barrier();
    }
  }

#pragma unroll
  for (int mi = 0; mi < MREP; ++mi)
#pragma unroll
    for (int ni = 0; ni < 4; ++ni) {
      int rb = row0 + wrow + mi * 16 + g * 4;
      int cc = col0 + wcol + ni * 16 + lr;
#pragma unroll
      for (int r = 0; r < 4; ++r) C[(size_t)(rb + r) * N + cc] = (OutT)acc[mi][ni][r];
    }
}

// ---- merged post-pass: QK RMS-norm (blocks 0..4095) + V permute (4096..4607)
__global__ __launch_bounds__(256) void k_post(bf16* __restrict__ qkv,
                                              const float* __restrict__ qs,
                                              const float* __restrict__ ks,
                                              bf16* __restrict__ Vt) {
  int bid = blockIdx.x, tid = threadIdx.x;
  if (bid < 4096) {
    int tok = bid;
    int wid = tid >> 6, lane = tid & 63;
    int d = lane * 2;
    bf16* rowp = qkv + (size_t)tok * 3072;
#pragma unroll
    for (int i = 0; i < 5; ++i) {
      int cb = (i < 4) ? (wid + i * 4) * 128 : 2048 + wid * 128;
      float v0 = (float)rowp[cb + d], v1 = (float)rowp[cb + d + 1];
      float ss = v0 * v0 + v1 * v1;
#pragma unroll
      for (int off = 1; off < 64; off <<= 1) ss += __shfl_xor(ss, off);
      float r = rsqrtf(ss * (1.0f / 128.0f) + 1e-6f);
      float s0, s1, extra;
      if (i < 4) {
        s0 = qs[d]; s1 = qs[d + 1];
        extra = 0.08838834764831845f * 1.4426950408889634f;  // rsqrt(d)*log2e
      } else {
        s0 = ks[d]; s1 = ks[d + 1]; extra = 1.0f;
      }
      rowp[cb + d] = (bf16)(v0 * r * s0 * extra);
      rowp[cb + d + 1] = (bf16)(v1 * r * s1 * extra);
    }
    return;
  }
  __shared__ bf16 t[64 * 65];
  int f = bid - 4096;           // 0..511
  int t0 = (f & 31) * 64;
  int d0 = ((f >> 5) & 1) * 64;
  int bh = f >> 6;
  int b = bh >> 2, kvh = bh & 3;
  const bf16* src = qkv + (size_t)(b * 2048) * 3072 + 2560 + kvh * 128;
  bf16* dst = Vt + (size_t)bh * 262144 + (size_t)(t0 >> 6) * 8192;
#pragma unroll
  for (int i = 0; i < 16; ++i) {
    int ff = i * 256 + tid;
    int tl = ff >> 6, dl = ff & 63;
    t[tl * 65 + dl] = src[(size_t)(t0 + tl) * 3072 + d0 + dl];
  }
  __syncthreads();
#pragma unroll
  for (int i = 0; i < 2; ++i) {
    int v = i * 256 + tid;
    int c = v >> 6, dv = v & 63;
    bf16x8 o;
#pragma unroll
    for (int j = 0; j < 8; ++j) o[j] = t[(c * 8 + j) * 65 + dv];
    *(bf16x8*)&dst[(size_t)c * 1024 + (size_t)(d0 + dv) * 8] = o;
  }
}

__device__ inline unsigned pack2bf(float a, float b) {
  union { bf16 h[2]; unsigned u; } x;
  x.h[0] = (bf16)a;
  x.h[1] = (bf16)b;
  return x.u;
}

// ---------------- causal GQA flash attention (swapped QK, 32x32 MFMA) ------
__global__ __launch_bounds__(256, 2) void k_attn(const bf16* __restrict__ qkv,
                                                 const bf16* __restrict__ Vt,
                                                 bf16* __restrict__ y) {
  int flat = blockIdx.x;
  int slot = flat >> 8;
  int j = flat & 255;
  int xcd = j & 7, iw = j >> 3;
  int h = xcd + 8 * (iw & 1);
  int r = iw >> 1;
  int b = r & 1;
  int qt = slot ? (r >> 1) : (15 - (r >> 1));
  int kvh = h >> 2;
  int tid = threadIdx.x;
  int wid = tid >> 6, lane = tid & 63;
  int qc = lane & 31, hi = lane >> 5;
  __shared__ alignas(16) bf16 Ks[2][16 * 64 * 8];
  __shared__ alignas(16) bf16 Vs[2][8 * 128 * 8];
  const bf16* Qb = qkv + (size_t)(b * 2048) * 3072 + h * 128;
  const bf16* Kb = qkv + (size_t)(b * 2048) * 3072 + 2048 + kvh * 128;
  const bf16* Vb = Vt + (size_t)(b * 4 + kvh) * 262144;
  int qw0 = qt * 128 + wid * 32;
  int qg = qw0 + qc;
  bf16x8 qf[8];
#pragma unroll
  for (int s = 0; s < 8; ++s)
    qf[s] = *(const bf16x8*)&Qb[(size_t)qg * 3072 + s * 16 + hi * 8];
  f32x16 acc[4] = {};
  float mrun = -1e30f, lrun = 0.f;

  auto STAGE = [&](int buf, int kt2) {
    int s0 = kt2 * 64;
#pragma unroll
    for (int i = 0; i < 4; ++i) {
      int sl = i * 256 + tid;
      int ch = sl >> 6, row = sl & 63;
      LOAD_LDS16(Kb + (size_t)(s0 + row) * 3072 + ch * 8, &Ks[buf][sl * 8]);
    }
#pragma unroll
    for (int i = 0; i < 4; ++i) {
      int sl = i * 256 + tid;
      LOAD_LDS16(Vb + (size_t)kt2 * 8192 + sl * 8, &Vs[buf][sl * 8]);
    }
  };

  STAGE(0, 0);
  int cur = 0;
  int ktmax = 2 * qt + 1;
  for (int kt = 0; kt <= ktmax; ++kt) {
    int s0 = kt * 64;
    if (kt < ktmax) {
      STAGE(cur ^ 1, kt + 1);
      asm volatile("s_waitcnt vmcnt(8)" ::: "memory");
    } else {
      asm volatile("s_waitcnt vmcnt(0)" ::: "memory");
    }
    __builtin_amdgcn_s_barrier();
    __builtin_amdgcn_sched_barrier(0);
    if (s0 <= qw0 + 31) {
      f32x16 sc[2] = {};
      __builtin_amdgcn_s_setprio(1);
#pragma unroll
      for (int s = 0; s < 8; ++s)
#pragma unroll
        for (int n = 0; n < 2; ++n) {
          bf16x8 kf =
              *(const bf16x8*)&Ks[cur][(((2 * s + hi) << 6) + n * 32 + qc) * 8];
          sc[n] =
              __builtin_amdgcn_mfma_f32_32x32x16_bf16(kf, qf[s], sc[n], 0, 0, 0);
        }
      __builtin_amdgcn_s_setprio(0);
      if (s0 + 63 > qw0) {
#pragma unroll
        for (int n = 0; n < 2; ++n)
#pragma unroll
          for (int r2 = 0; r2 < 16; ++r2) {
            int kg = s0 + n * 32 + (r2 & 3) + 8 * (r2 >> 2) + 4 * hi;
            if (kg > qg) sc[n][r2] = -1e30f;
          }
      }
      float pm = -1e30f;
#pragma unroll
      for (int n = 0; n < 2; ++n)
#pragma unroll
        for (int r2 = 0; r2 < 16; ++r2) pm = fmaxf(pm, sc[n][r2]);
      pm = fmaxf(pm, __shfl_xor(pm, 32));
      if (__any(pm > mrun + 11.0f)) {
        float mnew = fmaxf(mrun, pm);
        float scl = EXP2F(mrun - mnew);
        mrun = mnew;
        lrun *= scl;
        float sv[16];
#pragma unroll
        for (int r2 = 0; r2 < 16; ++r2)
          sv[r2] = __shfl(scl, (r2 & 3) + 8 * (r2 >> 2) + 4 * hi);
#pragma unroll
        for (int dt = 0; dt < 4; ++dt)
#pragma unroll
          for (int r2 = 0; r2 < 16; ++r2) acc[dt][r2] *= sv[r2];
      }
      float rs = 0.f;
#pragma unroll
      for (int n = 0; n < 2; ++n) {
        unsigned pk[8];
#pragma unroll
        for (int mm = 0; mm < 8; ++mm) {
          float e0 = EXP2F(sc[n][2 * mm] - mrun);
          float e1 = EXP2F(sc[n][2 * mm + 1] - mrun);
          rs += e0 + e1;
          pk[mm] = pack2bf(e0, e1);
        }
#pragma unroll
        for (int l2 = 0; l2 < 2; ++l2) {
          unsigned a0 = pk[4 * l2 + 0], b0 = pk[4 * l2 + 2];
          unsigned a1 = pk[4 * l2 + 1], b1 = pk[4 * l2 + 3];
          asm volatile("v_permlane32_swap_b32 %0, %1" : "+v"(a0), "+v"(b0));
          asm volatile("v_permlane32_swap_b32 %0, %1" : "+v"(a1), "+v"(b1));
          u32x4 w = {a0, a1, b0, b1};
          bf16x8 pf = __builtin_bit_cast(bf16x8, w);
          int c = 2 * (2 * n + l2) + hi;
          __builtin_amdgcn_s_setprio(1);
#pragma unroll
          for (int dt = 0; dt < 4; ++dt) {
            bf16x8 vf =
                *(const bf16x8*)&Vs[cur][((c << 7) + dt * 32 + qc) * 8];
            acc[dt] =
                __builtin_amdgcn_mfma_f32_32x32x16_bf16(pf, vf, acc[dt], 0, 0, 0);
          }
          __builtin_amdgcn_s_setprio(0);
        }
      }
      rs += __shfl_xor(rs, 32);
      lrun += rs;
    }
    __builtin_amdgcn_sched_barrier(0);
    __builtin_amdgcn_s_barrier();
    cur ^= 1;
  }
  float rlv = 1.0f / lrun;
  float rcl[16];
#pragma unroll
  for (int r2 = 0; r2 < 16; ++r2)
    rcl[r2] = __shfl(rlv, (r2 & 3) + 8 * (r2 >> 2) + 4 * hi);
#pragma unroll
  for (int dt = 0; dt < 4; ++dt)
#pragma unroll
    for (int r2 = 0; r2 < 16; ++r2) {
      int row = qw0 + (r2 & 3) + 8 * (r2 >> 2) + 4 * hi;
      float v = acc[dt][r2] * rcl[r2];
      y[(size_t)(b * 2048 + row) * 2048 + h * 128 + dt * 32 + qc] = (bf16)v;
    }
}

// ---------------- launcher ----------------
extern "C" void kernel_launch(void* const* d_in, const int* in_sizes, int n_in,
                              void* d_out, int out_size, void* d_ws,
                              size_t ws_size, hipStream_t stream) {
  const float* x = (const float*)d_in[0];
  const float* Wqkv = (const float*)d_in[1];
  const float* Wproj = (const float*)d_in[2];
  const float* qs = (const float*)d_in[3];
  const float* ks = (const float*)d_in[4];
  float* out = (float*)d_out;
  char* ws = (char*)d_ws;

  bf16* xb = (bf16*)(ws);
  bf16* Wqkvt = (bf16*)(ws + (size_t)(16u << 20));
  bf16* Wprojt = (bf16*)(ws + (size_t)(28u << 20));
  bf16* qkv = (bf16*)(ws + (size_t)(36u << 20));
  bf16* Vt = Wqkvt;  // reuse after Wqkvt consumed by G1
  bf16* y = xb;      // reuse after xb consumed by G1

  k_pre<<<10752, 256, 0, stream>>>(x, Wqkv, Wproj, xb, Wqkvt, Wprojt);
  k_gemm256<bf16, 256><<<dim3(16, 12), 512, 0, stream>>>(xb, Wqkvt, qkv, 4096, 3072, 2048);
  k_post<<<4608, 256, 0, stream>>>(qkv, qs, ks, Vt);
  k_attn<<<dim3(512, 1, 1), 256, 0, stream>>>(qkv, Vt, y);
  k_gemm256<float, 128><<<dim3(32, 8), 512, 0, stream>>>(y, Wprojt, out, 4096, 2048, 2048);
}

// Round 18
// 246.523 us; speedup vs baseline: 1.1089x; 1.1089x over previous
//
#include <hip/hip_runtime.h>

typedef __bf16 bf16;
typedef __bf16 bf16x8 __attribute__((ext_vector_type(8)));
typedef __bf16 bf16x4 __attribute__((ext_vector_type(4)));
typedef float f32x4 __attribute__((ext_vector_type(4)));
typedef float f32x16 __attribute__((ext_vector_type(16)));
typedef unsigned u32x4 __attribute__((ext_vector_type(4)));

#define EXP2F(x) __builtin_amdgcn_exp2f(x)

#define LOAD_LDS16(gp, lp)                                                     \
  __builtin_amdgcn_global_load_lds(                                            \
      (const __attribute__((address_space(1))) void*)(gp),                     \
      (__attribute__((address_space(3))) void*)(lp), 16, 0, 0)

// ---- merged pre-pass: x f32->bf16 cvt + Wqkv/Wproj transpose to [N][K] ----
__global__ __launch_bounds__(256) void k_pre(const float* __restrict__ x,
                                             const float* __restrict__ Wqkv,
                                             const float* __restrict__ Wproj,
                                             bf16* __restrict__ xb,
                                             bf16* __restrict__ Wqkvt,
                                             bf16* __restrict__ Wprojt) {
  int bid = blockIdx.x, tid = threadIdx.x;
  if (bid < 8192) {
    int i = bid * 256 + tid;
    float4 v = ((const float4*)x)[i];
    bf16x4 o = {(bf16)v.x, (bf16)v.y, (bf16)v.z, (bf16)v.w};
    ((bf16x4*)xb)[i] = o;
    return;
  }
  __shared__ bf16 t[64 * 65];
  const float* in;
  bf16* out;
  int R, C, c0, r0;
  if (bid < 9728) {
    int f = bid - 8192;
    in = Wqkv; out = Wqkvt; R = 2048; C = 3072;
    c0 = (f % 48) * 64; r0 = (f / 48) * 64;
  } else {
    int f = bid - 9728;
    in = Wproj; out = Wprojt; R = 2048; C = 2048;
    c0 = (f & 31) * 64; r0 = (f >> 5) * 64;
  }
#pragma unroll
  for (int i = 0; i < 16; ++i) {
    int f = i * 256 + tid;
    int rl = f >> 6, cl = f & 63;
    t[rl * 65 + cl] = (bf16)in[(size_t)(r0 + rl) * C + c0 + cl];
  }
  __syncthreads();
#pragma unroll
  for (int i = 0; i < 16; ++i) {
    int f = i * 256 + tid;
    int cl = f >> 6, rl = f & 63;
    out[(size_t)(c0 + cl) * R + r0 + rl] = t[rl * 65 + cl];
  }
}

// ---- bf16 GEMM, BMx256 tile — round-7/11 validated schedule ----
template <typename OutT, int BM>
__global__ __launch_bounds__(512, 2) void k_gemm256(const bf16* __restrict__ A,
                                                    const bf16* __restrict__ Bt,
                                                    OutT* __restrict__ C,
                                                    int M, int N, int K) {
  constexpr int ASZ = 4 * BM * 8;
  constexpr int MREP = BM / 32;
  __shared__ alignas(16) bf16 As[2][2][ASZ];
  __shared__ alignas(16) bf16 Bs[2][2][4 * 256 * 8];
  int tid = threadIdx.x;
  int wid = tid >> 6, lane = tid & 63;
  int g = lane >> 4, lr = lane & 15;
  int wrow = (wid >> 2) * (BM / 2), wcol = (wid & 3) * 64;
  int gx = gridDim.x;
  int flat = blockIdx.y * gx + blockIdx.x;
  int cpx = (gx * gridDim.y) >> 3;
  int f2 = (flat & 7) * cpx + (flat >> 3);
  int row0 = (f2 % gx) * BM, col0 = (f2 / gx) * 256;
  int NT = K >> 6;
  f32x4 acc[MREP][4] = {};

  auto stageA = [&](int buf, int kh, int kt) {
#pragma unroll
    for (int pass = 0; pass < BM / 128; ++pass) {
      int slot = pass * 512 + tid;
      int kseg, row;
      if constexpr (BM == 256) { kseg = slot >> 8; row = slot & 255; }
      else { kseg = slot >> 7; row = slot & 127; }
      LOAD_LDS16(A + (size_t)(row0 + row) * K + kt * 64 + kh * 32 + kseg * 8,
                 &As[buf][kh][slot * 8]);
    }
  };
  auto stageB = [&](int buf, int kh, int kt) {
#pragma unroll
    for (int pass = 0; pass < 2; ++pass) {
      int slot = pass * 512 + tid;
      int kseg = slot >> 8, row = slot & 255;
      LOAD_LDS16(Bt + (size_t)(col0 + row) * K + kt * 64 + kh * 32 + kseg * 8,
                 &Bs[buf][kh][slot * 8]);
    }
  };
  auto dsA = [&](int buf, int s, int mq, bf16x8* af) {
#pragma unroll
    for (int i = 0; i < 4; ++i)
      af[i] = *(const bf16x8*)&As[buf][s]
                  [(g * BM + wrow + (mq * 4 + i) * 16 + lr) * 8];
  };
  auto dsB = [&](int buf, int s, bf16x8* bfr) {
#pragma unroll
    for (int i = 0; i < 4; ++i)
      bfr[i] = *(const bf16x8*)&Bs[buf][s][((g << 8) + wcol + i * 16 + lr) * 8];
  };
  auto mfma16 = [&](int mq, bf16x8* af, bf16x8* bfr) {
    __builtin_amdgcn_s_setprio(1);
#pragma unroll
    for (int i = 0; i < 4; ++i)
#pragma unroll
      for (int n = 0; n < 4; ++n)
        acc[mq * 4 + i][n] = __builtin_amdgcn_mfma_f32_16x16x32_bf16(
            af[i], bfr[n], acc[mq * 4 + i][n], 0, 0, 0);
    __builtin_amdgcn_s_setprio(0);
  };

  stageA(0, 0, 0);
  stageB(0, 0, 0);
  stageA(0, 1, 0);
  stageB(0, 1, 0);
  if constexpr (BM == 256)
    asm volatile("s_waitcnt vmcnt(4)" ::: "memory");
  else
    asm volatile("s_waitcnt vmcnt(3)" ::: "memory");
  __builtin_amdgcn_s_barrier();

  for (int T = 0; T < NT; ++T) {
    int buf = T & 1, nbuf = buf ^ 1;
    bool more = (T + 1 < NT);
    bf16x8 af[4], bfr[4];
    if constexpr (BM == 256) {
      dsA(buf, 0, 0, af);
      dsB(buf, 0, bfr);
      if (more) stageA(nbuf, 0, T + 1);
      __builtin_amdgcn_s_barrier();
      mfma16(0, af, bfr);
      __builtin_amdgcn_s_barrier();
      dsA(buf, 0, 1, af);
      if (more) {
        stageB(nbuf, 0, T + 1);
        asm volatile("s_waitcnt vmcnt(4)" ::: "memory");
      } else {
        asm volatile("s_waitcnt vmcnt(0)" ::: "memory");
      }
      __builtin_amdgcn_s_barrier();
      mfma16(1, af, bfr);
      __builtin_amdgcn_s_barrier();
      dsA(buf, 1, 0, af);
      dsB(buf, 1, bfr);
      if (more) stageA(nbuf, 1, T + 1);
      __builtin_amdgcn_s_barrier();
      mfma16(0, af, bfr);
      __builtin_amdgcn_s_barrier();
      dsA(buf, 1, 1, af);
      if (more) {
        stageB(nbuf, 1, T + 1);
        asm volatile("s_waitcnt vmcnt(4)" ::: "memory");
      }
      __builtin_amdgcn_s_barrier();
      mfma16(1, af, bfr);
      __builtin_amdgcn_s_barrier();
    } else {
      dsA(buf, 0, 0, af);
      dsB(buf, 0, bfr);
      if (more) {
        stageA(nbuf, 0, T + 1);
        stageB(nbuf, 0, T + 1);
        asm volatile("s_waitcnt vmcnt(3)" ::: "memory");
      } else {
        asm volatile("s_waitcnt vmcnt(0)" ::: "memory");
      }
      __builtin_amdgcn_s_barrier();
      mfma16(0, af, bfr);
      __builtin_amdgcn_s_barrier();
      dsA(buf, 1, 0, af);
      dsB(buf, 1, bfr);
      if (more) {
        stageA(nbuf, 1, T + 1);
        stageB(nbuf, 1, T + 1);
        asm volatile("s_waitcnt vmcnt(3)" ::: "memory");
      }
      __builtin_amdgcn_s_barrier();
      mfma16(0, af, bfr);
      __builtin_amdgcn_s_barrier();
    }
  }

#pragma unroll
  for (int mi = 0; mi < MREP; ++mi)
#pragma unroll
    for (int ni = 0; ni < 4; ++ni) {
      int rb = row0 + wrow + mi * 16 + g * 4;
      int cc = col0 + wcol + ni * 16 + lr;
#pragma unroll
      for (int r = 0; r < 4; ++r) C[(size_t)(rb + r) * N + cc] = (OutT)acc[mi][ni][r];
    }
}

// ---- merged post-pass: QK RMS-norm (blocks 0..4095) + V permute (4096..4607)
__global__ __launch_bounds__(256) void k_post(bf16* __restrict__ qkv,
                                              const float* __restrict__ qs,
                                              const float* __restrict__ ks,
                                              bf16* __restrict__ Vt) {
  int bid = blockIdx.x, tid = threadIdx.x;
  if (bid < 4096) {
    int tok = bid;
    int wid = tid >> 6, lane = tid & 63;
    int d = lane * 2;
    bf16* rowp = qkv + (size_t)tok * 3072;
#pragma unroll
    for (int i = 0; i < 5; ++i) {
      int cb = (i < 4) ? (wid + i * 4) * 128 : 2048 + wid * 128;
      float v0 = (float)rowp[cb + d], v1 = (float)rowp[cb + d + 1];
      float ss = v0 * v0 + v1 * v1;
#pragma unroll
      for (int off = 1; off < 64; off <<= 1) ss += __shfl_xor(ss, off);
      float r = rsqrtf(ss * (1.0f / 128.0f) + 1e-6f);
      float s0, s1, extra;
      if (i < 4) {
        s0 = qs[d]; s1 = qs[d + 1];
        extra = 0.08838834764831845f * 1.4426950408889634f;  // rsqrt(d)*log2e
      } else {
        s0 = ks[d]; s1 = ks[d + 1]; extra = 1.0f;
      }
      rowp[cb + d] = (bf16)(v0 * r * s0 * extra);
      rowp[cb + d + 1] = (bf16)(v1 * r * s1 * extra);
    }
    return;
  }
  // V transpose -> Vt[bh][kt(32)][c(8)][d(128)][8]
  __shared__ bf16 t[64 * 65];
  int f = bid - 4096;           // 0..511
  int t0 = (f & 31) * 64;
  int d0 = ((f >> 5) & 1) * 64;
  int bh = f >> 6;
  int b = bh >> 2, kvh = bh & 3;
  const bf16* src = qkv + (size_t)(b * 2048) * 3072 + 2560 + kvh * 128;
  bf16* dst = Vt + (size_t)bh * 262144 + (size_t)(t0 >> 6) * 8192;
#pragma unroll
  for (int i = 0; i < 16; ++i) {
    int ff = i * 256 + tid;
    int tl = ff >> 6, dl = ff & 63;
    t[tl * 65 + dl] = src[(size_t)(t0 + tl) * 3072 + d0 + dl];
  }
  __syncthreads();
#pragma unroll
  for (int i = 0; i < 2; ++i) {
    int v = i * 256 + tid;
    int c = v >> 6, dv = v & 63;
    bf16x8 o;
#pragma unroll
    for (int j = 0; j < 8; ++j) o[j] = t[(c * 8 + j) * 65 + dv];
    *(bf16x8*)&dst[(size_t)c * 1024 + (size_t)(d0 + dv) * 8] = o;
  }
}

__device__ inline unsigned pack2bf(float a, float b) {
  union { bf16 h[2]; unsigned u; } x;
  x.h[0] = (bf16)a;
  x.h[1] = (bf16)b;
  return x.u;
}

// ---------------- causal GQA flash attention (swapped QK, 32x32 MFMA) ------
// Round-11/13/14/15-validated: 512 blocks, 4 waves, QBLK=128, complementary
// qt decode, conflict-free V LDS [c][d][8], s_setprio around MFMA clusters.
__global__ __launch_bounds__(256, 2) void k_attn(const bf16* __restrict__ qkv,
                                                 const bf16* __restrict__ Vt,
                                                 bf16* __restrict__ y) {
  int flat = blockIdx.x;
  int slot = flat >> 8;                 // 0 = heavy half, 1 = light half
  int j = flat & 255;
  int xcd = j & 7, iw = j >> 3;         // iw 0..31
  int h = xcd + 8 * (iw & 1);
  int r = iw >> 1;                      // 0..15
  int b = r & 1;
  int qt = slot ? (r >> 1) : (15 - (r >> 1));
  int kvh = h >> 2;
  int tid = threadIdx.x;
  int wid = tid >> 6, lane = tid & 63;
  int qc = lane & 31, hi = lane >> 5;
  __shared__ alignas(16) bf16 Ks[2][16 * 64 * 8];  // 2 x 16KB
  __shared__ alignas(16) bf16 Vs[2][8 * 128 * 8];  // 2 x 16KB, [c][d][8]
  const bf16* Qb = qkv + (size_t)(b * 2048) * 3072 + h * 128;
  const bf16* Kb = qkv + (size_t)(b * 2048) * 3072 + 2048 + kvh * 128;
  const bf16* Vb = Vt + (size_t)(b * 4 + kvh) * 262144;
  int qw0 = qt * 128 + wid * 32;
  int qg = qw0 + qc;
  bf16x8 qf[8];
#pragma unroll
  for (int s = 0; s < 8; ++s)
    qf[s] = *(const bf16x8*)&Qb[(size_t)qg * 3072 + s * 16 + hi * 8];
  f32x16 acc[4] = {};
  float mrun = -1e30f, lrun = 0.f;

  auto STAGE = [&](int buf, int kt2) {
    int s0 = kt2 * 64;
#pragma unroll
    for (int i = 0; i < 4; ++i) {  // K: slot = chunk*64+row
      int sl = i * 256 + tid;
      int ch = sl >> 6, row = sl & 63;
      LOAD_LDS16(Kb + (size_t)(s0 + row) * 3072 + ch * 8, &Ks[buf][sl * 8]);
    }
#pragma unroll
    for (int i = 0; i < 4; ++i) {  // V: linear from pre-permuted Vt
      int sl = i * 256 + tid;
      LOAD_LDS16(Vb + (size_t)kt2 * 8192 + sl * 8, &Vs[buf][sl * 8]);
    }
  };

  STAGE(0, 0);
  int cur = 0;
  int ktmax = 2 * qt + 1;
  for (int kt = 0; kt <= ktmax; ++kt) {
    int s0 = kt * 64;
    if (kt < ktmax) {
      STAGE(cur ^ 1, kt + 1);
      asm volatile("s_waitcnt vmcnt(8)" ::: "memory");
    } else {
      asm volatile("s_waitcnt vmcnt(0)" ::: "memory");
    }
    __builtin_amdgcn_s_barrier();
    __builtin_amdgcn_sched_barrier(0);
    if (s0 <= qw0 + 31) {
      f32x16 sc[2] = {};
      __builtin_amdgcn_s_setprio(1);
#pragma unroll
      for (int s = 0; s < 8; ++s)
#pragma unroll
        for (int n = 0; n < 2; ++n) {
          bf16x8 kf =
              *(const bf16x8*)&Ks[cur][(((2 * s + hi) << 6) + n * 32 + qc) * 8];
          sc[n] =
              __builtin_amdgcn_mfma_f32_32x32x16_bf16(kf, qf[s], sc[n], 0, 0, 0);
        }
      __builtin_amdgcn_s_setprio(0);
      if (s0 + 63 > qw0) {
#pragma unroll
        for (int n = 0; n < 2; ++n)
#pragma unroll
          for (int r2 = 0; r2 < 16; ++r2) {
            int kg = s0 + n * 32 + (r2 & 3) + 8 * (r2 >> 2) + 4 * hi;
            if (kg > qg) sc[n][r2] = -1e30f;
          }
      }
      float pm = -1e30f;
#pragma unroll
      for (int n = 0; n < 2; ++n)
#pragma unroll
        for (int r2 = 0; r2 < 16; ++r2) pm = fmaxf(pm, sc[n][r2]);
      pm = fmaxf(pm, __shfl_xor(pm, 32));
      if (__any(pm > mrun + 11.0f)) {
        float mnew = fmaxf(mrun, pm);
        float scl = EXP2F(mrun - mnew);
        mrun = mnew;
        lrun *= scl;
        float sv[16];
#pragma unroll
        for (int r2 = 0; r2 < 16; ++r2)
          sv[r2] = __shfl(scl, (r2 & 3) + 8 * (r2 >> 2) + 4 * hi);
#pragma unroll
        for (int dt = 0; dt < 4; ++dt)
#pragma unroll
          for (int r2 = 0; r2 < 16; ++r2) acc[dt][r2] *= sv[r2];
      }
      float rs = 0.f;
#pragma unroll
      for (int n = 0; n < 2; ++n) {
        unsigned pk[8];
#pragma unroll
        for (int mm = 0; mm < 8; ++mm) {
          float e0 = EXP2F(sc[n][2 * mm] - mrun);
          float e1 = EXP2F(sc[n][2 * mm + 1] - mrun);
          rs += e0 + e1;
          pk[mm] = pack2bf(e0, e1);
        }
#pragma unroll
        for (int l2 = 0; l2 < 2; ++l2) {
          unsigned a0 = pk[4 * l2 + 0], b0 = pk[4 * l2 + 2];
          unsigned a1 = pk[4 * l2 + 1], b1 = pk[4 * l2 + 3];
          asm volatile("v_permlane32_swap_b32 %0, %1" : "+v"(a0), "+v"(b0));
          asm volatile("v_permlane32_swap_b32 %0, %1" : "+v"(a1), "+v"(b1));
          u32x4 w = {a0, a1, b0, b1};
          bf16x8 pf = __builtin_bit_cast(bf16x8, w);
          int c = 2 * (2 * n + l2) + hi;  // t-chunk index
          __builtin_amdgcn_s_setprio(1);
#pragma unroll
          for (int dt = 0; dt < 4; ++dt) {
            bf16x8 vf =
                *(const bf16x8*)&Vs[cur][((c << 7) + dt * 32 + qc) * 8];
            acc[dt] =
                __builtin_amdgcn_mfma_f32_32x32x16_bf16(pf, vf, acc[dt], 0, 0, 0);
          }
          __builtin_amdgcn_s_setprio(0);
        }
      }
      rs += __shfl_xor(rs, 32);
      lrun += rs;
    }
    __builtin_amdgcn_sched_barrier(0);
    __builtin_amdgcn_s_barrier();
    cur ^= 1;
  }
  float rlv = 1.0f / lrun;
  float rcl[16];
#pragma unroll
  for (int r2 = 0; r2 < 16; ++r2)
    rcl[r2] = __shfl(rlv, (r2 & 3) + 8 * (r2 >> 2) + 4 * hi);
#pragma unroll
  for (int dt = 0; dt < 4; ++dt)
#pragma unroll
    for (int r2 = 0; r2 < 16; ++r2) {
      int row = qw0 + (r2 & 3) + 8 * (r2 >> 2) + 4 * hi;
      float v = acc[dt][r2] * rcl[r2];
      y[(size_t)(b * 2048 + row) * 2048 + h * 128 + dt * 32 + qc] = (bf16)v;
    }
}

// ---------------- launcher ----------------
extern "C" void kernel_launch(void* const* d_in, const int* in_sizes, int n_in,
                              void* d_out, int out_size, void* d_ws,
                              size_t ws_size, hipStream_t stream) {
  const float* x = (const float*)d_in[0];
  const float* Wqkv = (const float*)d_in[1];
  const float* Wproj = (const float*)d_in[2];
  const float* qs = (const float*)d_in[3];
  const float* ks = (const float*)d_in[4];
  float* out = (float*)d_out;
  char* ws = (char*)d_ws;

  bf16* xb = (bf16*)(ws);
  bf16* Wqkvt = (bf16*)(ws + (size_t)(16u << 20));
  bf16* Wprojt = (bf16*)(ws + (size_t)(28u << 20));
  bf16* qkv = (bf16*)(ws + (size_t)(36u << 20));
  bf16* Vt = Wqkvt;  // reuse after Wqkvt consumed by G1
  bf16* y = xb;      // reuse after xb consumed by G1

  k_pre<<<10752, 256, 0, stream>>>(x, Wqkv, Wproj, xb, Wqkvt, Wprojt);
  k_gemm256<bf16, 256><<<dim3(16, 12), 512, 0, stream>>>(xb, Wqkvt, qkv, 4096, 3072, 2048);
  k_post<<<4608, 256, 0, stream>>>(qkv, qs, ks, Vt);
  k_attn<<<dim3(512, 1, 1), 256, 0, stream>>>(qkv, Vt, y);
  k_gemm256<float, 128><<<dim3(32, 8), 512, 0, stream>>>(y, Wprojt, out, 4096, 2048, 2048);
}

// Round 19
// 242.402 us; speedup vs baseline: 1.1278x; 1.0170x over previous
//
#include <hip/hip_runtime.h>

typedef __bf16 bf16;
typedef __bf16 bf16x8 __attribute__((ext_vector_type(8)));
typedef __bf16 bf16x4 __attribute__((ext_vector_type(4)));
typedef float f32x4 __attribute__((ext_vector_type(4)));
typedef float f32x16 __attribute__((ext_vector_type(16)));
typedef unsigned u32x4 __attribute__((ext_vector_type(4)));

#define EXP2F(x) __builtin_amdgcn_exp2f(x)

#define LOAD_LDS16(gp, lp)                                                     \
  __builtin_amdgcn_global_load_lds(                                            \
      (const __attribute__((address_space(1))) void*)(gp),                     \
      (__attribute__((address_space(3))) void*)(lp), 16, 0, 0)

// ---- merged pre-pass: x f32->bf16 cvt (16B stores) + Wqkv transpose -------
// blocks [0,4096): cvt, bf16x8 per thread; [4096,5632): Wqkv 2048x3072
// transpose with bf16x4 vectorized writes.
__global__ __launch_bounds__(256) void k_pre(const float* __restrict__ x,
                                             const float* __restrict__ Wqkv,
                                             bf16* __restrict__ xb,
                                             bf16* __restrict__ Wqkvt) {
  int bid = blockIdx.x, tid = threadIdx.x;
  if (bid < 4096) {
    int i = bid * 256 + tid;
    float4 v0 = ((const float4*)x)[2 * i];
    float4 v1 = ((const float4*)x)[2 * i + 1];
    bf16x8 o = {(bf16)v0.x, (bf16)v0.y, (bf16)v0.z, (bf16)v0.w,
                (bf16)v1.x, (bf16)v1.y, (bf16)v1.z, (bf16)v1.w};
    ((bf16x8*)xb)[i] = o;
    return;
  }
  __shared__ bf16 t[64 * 65];
  int f = bid - 4096;                 // 0..1535
  int c0 = (f % 48) * 64, r0 = (f / 48) * 64;
  const int C = 3072, R = 2048;
#pragma unroll
  for (int i = 0; i < 16; ++i) {
    int f2 = i * 256 + tid;
    int rl = f2 >> 6, cl = f2 & 63;
    t[rl * 65 + cl] = (bf16)Wqkv[(size_t)(r0 + rl) * C + c0 + cl];
  }
  __syncthreads();
#pragma unroll
  for (int i = 0; i < 4; ++i) {
    int idx = i * 256 + tid;          // 1024 vec4 writes
    int cl = idx >> 4, rl0 = (idx & 15) * 4;
    bf16x4 o = {t[(rl0 + 0) * 65 + cl], t[(rl0 + 1) * 65 + cl],
                t[(rl0 + 2) * 65 + cl], t[(rl0 + 3) * 65 + cl]};
    *(bf16x4*)&Wqkvt[(size_t)(c0 + cl) * R + r0 + rl0] = o;
  }
}

// ---- bf16 GEMM, BMx256 tile — round-7/11 validated schedule ----
// Extra: blocks with flat >= ntiles run the Wproj transpose on otherwise-idle
// CUs (QKV launch only: grid 256, ntiles 192). Proj launch: grid == ntiles.
template <typename OutT, int BM>
__global__ __launch_bounds__(512, 2) void k_gemm256(const bf16* __restrict__ A,
                                                    const bf16* __restrict__ Bt,
                                                    OutT* __restrict__ C,
                                                    int M, int N, int K,
                                                    const float* __restrict__ Wp,
                                                    bf16* __restrict__ Wpt) {
  constexpr int ASZ = 4 * BM * 8;
  constexpr int MREP = BM / 32;
  __shared__ alignas(16) bf16 As[2][2][ASZ];
  __shared__ alignas(16) bf16 Bs[2][2][4 * 256 * 8];
  int tid = threadIdx.x;
  int wid = tid >> 6, lane = tid & 63;
  int g = lane >> 4, lr = lane & 15;
  int wrow = (wid >> 2) * (BM / 2), wcol = (wid & 3) * 64;
  int gx = gridDim.x;
  int flat = blockIdx.y * gx + blockIdx.x;
  int ntiles = (M / BM) * (N / 256);
  if (flat >= ntiles) {
    // Wproj 2048x2048 transpose: fat block = 16 subtiles of 64x64, 512 thr.
    bf16* t = (bf16*)&As[0][0][0];    // alias; 8.3KB of the 64KB As region
    int b2 = flat - ntiles;           // 0..63
    for (int k = 0; k < 16; ++k) {
      int st = b2 * 16 + k;
      int c0 = (st & 31) * 64, r0 = (st >> 5) * 64;
#pragma unroll
      for (int i = 0; i < 8; ++i) {
        int f2 = i * 512 + tid;
        int rl = f2 >> 6, cl = f2 & 63;
        t[rl * 65 + cl] = (bf16)Wp[(size_t)(r0 + rl) * 2048 + c0 + cl];
      }
      __syncthreads();
#pragma unroll
      for (int i = 0; i < 2; ++i) {
        int idx = i * 512 + tid;      // 1024 vec4 writes
        int cl = idx >> 4, rl0 = (idx & 15) * 4;
        bf16x4 o = {t[(rl0 + 0) * 65 + cl], t[(rl0 + 1) * 65 + cl],
                    t[(rl0 + 2) * 65 + cl], t[(rl0 + 3) * 65 + cl]};
        *(bf16x4*)&Wpt[(size_t)(c0 + cl) * 2048 + r0 + rl0] = o;
      }
      __syncthreads();
    }
    return;
  }
  int cpx = ntiles >> 3;
  int f2 = (flat & 7) * cpx + (flat >> 3);
  int row0 = (f2 % gx) * BM, col0 = (f2 / gx) * 256;
  int NT = K >> 6;
  f32x4 acc[MREP][4] = {};

  auto stageA = [&](int buf, int kh, int kt) {
#pragma unroll
    for (int pass = 0; pass < BM / 128; ++pass) {
      int slot = pass * 512 + tid;
      int kseg, row;
      if constexpr (BM == 256) { kseg = slot >> 8; row = slot & 255; }
      else { kseg = slot >> 7; row = slot & 127; }
      LOAD_LDS16(A + (size_t)(row0 + row) * K + kt * 64 + kh * 32 + kseg * 8,
                 &As[buf][kh][slot * 8]);
    }
  };
  auto stageB = [&](int buf, int kh, int kt) {
#pragma unroll
    for (int pass = 0; pass < 2; ++pass) {
      int slot = pass * 512 + tid;
      int kseg = slot >> 8, row = slot & 255;
      LOAD_LDS16(Bt + (size_t)(col0 + row) * K + kt * 64 + kh * 32 + kseg * 8,
                 &Bs[buf][kh][slot * 8]);
    }
  };
  auto dsA = [&](int buf, int s, int mq, bf16x8* af) {
#pragma unroll
    for (int i = 0; i < 4; ++i)
      af[i] = *(const bf16x8*)&As[buf][s]
                  [(g * BM + wrow + (mq * 4 + i) * 16 + lr) * 8];
  };
  auto dsB = [&](int buf, int s, bf16x8* bfr) {
#pragma unroll
    for (int i = 0; i < 4; ++i)
      bfr[i] = *(const bf16x8*)&Bs[buf][s][((g << 8) + wcol + i * 16 + lr) * 8];
  };
  auto mfma16 = [&](int mq, bf16x8* af, bf16x8* bfr) {
    __builtin_amdgcn_s_setprio(1);
#pragma unroll
    for (int i = 0; i < 4; ++i)
#pragma unroll
      for (int n = 0; n < 4; ++n)
        acc[mq * 4 + i][n] = __builtin_amdgcn_mfma_f32_16x16x32_bf16(
            af[i], bfr[n], acc[mq * 4 + i][n], 0, 0, 0);
    __builtin_amdgcn_s_setprio(0);
  };

  stageA(0, 0, 0);
  stageB(0, 0, 0);
  stageA(0, 1, 0);
  stageB(0, 1, 0);
  if constexpr (BM == 256)
    asm volatile("s_waitcnt vmcnt(4)" ::: "memory");
  else
    asm volatile("s_waitcnt vmcnt(3)" ::: "memory");
  __builtin_amdgcn_s_barrier();

  for (int T = 0; T < NT; ++T) {
    int buf = T & 1, nbuf = buf ^ 1;
    bool more = (T + 1 < NT);
    bf16x8 af[4], bfr[4];
    if constexpr (BM == 256) {
      dsA(buf, 0, 0, af);
      dsB(buf, 0, bfr);
      if (more) stageA(nbuf, 0, T + 1);
      __builtin_amdgcn_s_barrier();
      mfma16(0, af, bfr);
      __builtin_amdgcn_s_barrier();
      dsA(buf, 0, 1, af);
      if (more) {
        stageB(nbuf, 0, T + 1);
        asm volatile("s_waitcnt vmcnt(4)" ::: "memory");
      } else {
        asm volatile("s_waitcnt vmcnt(0)" ::: "memory");
      }
      __builtin_amdgcn_s_barrier();
      mfma16(1, af, bfr);
      __builtin_amdgcn_s_barrier();
      dsA(buf, 1, 0, af);
      dsB(buf, 1, bfr);
      if (more) stageA(nbuf, 1, T + 1);
      __builtin_amdgcn_s_barrier();
      mfma16(0, af, bfr);
      __builtin_amdgcn_s_barrier();
      dsA(buf, 1, 1, af);
      if (more) {
        stageB(nbuf, 1, T + 1);
        asm volatile("s_waitcnt vmcnt(4)" ::: "memory");
      }
      __builtin_amdgcn_s_barrier();
      mfma16(1, af, bfr);
      __builtin_amdgcn_s_barrier();
    } else {
      dsA(buf, 0, 0, af);
      dsB(buf, 0, bfr);
      if (more) {
        stageA(nbuf, 0, T + 1);
        stageB(nbuf, 0, T + 1);
        asm volatile("s_waitcnt vmcnt(3)" ::: "memory");
      } else {
        asm volatile("s_waitcnt vmcnt(0)" ::: "memory");
      }
      __builtin_amdgcn_s_barrier();
      mfma16(0, af, bfr);
      __builtin_amdgcn_s_barrier();
      dsA(buf, 1, 0, af);
      dsB(buf, 1, bfr);
      if (more) {
        stageA(nbuf, 1, T + 1);
        stageB(nbuf, 1, T + 1);
        asm volatile("s_waitcnt vmcnt(3)" ::: "memory");
      }
      __builtin_amdgcn_s_barrier();
      mfma16(0, af, bfr);
      __builtin_amdgcn_s_barrier();
    }
  }

#pragma unroll
  for (int mi = 0; mi < MREP; ++mi)
#pragma unroll
    for (int ni = 0; ni < 4; ++ni) {
      int rb = row0 + wrow + mi * 16 + g * 4;
      int cc = col0 + wcol + ni * 16 + lr;
#pragma unroll
      for (int r = 0; r < 4; ++r) C[(size_t)(rb + r) * N + cc] = (OutT)acc[mi][ni][r];
    }
}

// ---- merged post-pass: QK RMS-norm (blocks 0..4095) + V permute (4096..4607)
__global__ __launch_bounds__(256) void k_post(bf16* __restrict__ qkv,
                                              const float* __restrict__ qs,
                                              const float* __restrict__ ks,
                                              bf16* __restrict__ Vt) {
  int bid = blockIdx.x, tid = threadIdx.x;
  if (bid < 4096) {
    int tok = bid;
    int wid = tid >> 6, lane = tid & 63;
    int d = lane * 2;
    bf16* rowp = qkv + (size_t)tok * 3072;
#pragma unroll
    for (int i = 0; i < 5; ++i) {
      int cb = (i < 4) ? (wid + i * 4) * 128 : 2048 + wid * 128;
      float v0 = (float)rowp[cb + d], v1 = (float)rowp[cb + d + 1];
      float ss = v0 * v0 + v1 * v1;
#pragma unroll
      for (int off = 1; off < 64; off <<= 1) ss += __shfl_xor(ss, off);
      float r = rsqrtf(ss * (1.0f / 128.0f) + 1e-6f);
      float s0, s1, extra;
      if (i < 4) {
        s0 = qs[d]; s1 = qs[d + 1];
        extra = 0.08838834764831845f * 1.4426950408889634f;  // rsqrt(d)*log2e
      } else {
        s0 = ks[d]; s1 = ks[d + 1]; extra = 1.0f;
      }
      rowp[cb + d] = (bf16)(v0 * r * s0 * extra);
      rowp[cb + d + 1] = (bf16)(v1 * r * s1 * extra);
    }
    return;
  }
  // V transpose -> Vt[bh][kt(32)][c(8)][d(128)][8]
  __shared__ bf16 t[64 * 65];
  int f = bid - 4096;           // 0..511
  int t0 = (f & 31) * 64;
  int d0 = ((f >> 5) & 1) * 64;
  int bh = f >> 6;
  int b = bh >> 2, kvh = bh & 3;
  const bf16* src = qkv + (size_t)(b * 2048) * 3072 + 2560 + kvh * 128;
  bf16* dst = Vt + (size_t)bh * 262144 + (size_t)(t0 >> 6) * 8192;
#pragma unroll
  for (int i = 0; i < 16; ++i) {
    int ff = i * 256 + tid;
    int tl = ff >> 6, dl = ff & 63;
    t[tl * 65 + dl] = src[(size_t)(t0 + tl) * 3072 + d0 + dl];
  }
  __syncthreads();
#pragma unroll
  for (int i = 0; i < 2; ++i) {
    int v = i * 256 + tid;
    int c = v >> 6, dv = v & 63;
    bf16x8 o;
#pragma unroll
    for (int j = 0; j < 8; ++j) o[j] = t[(c * 8 + j) * 65 + dv];
    *(bf16x8*)&dst[(size_t)c * 1024 + (size_t)(d0 + dv) * 8] = o;
  }
}

__device__ inline unsigned pack2bf(float a, float b) {
  union { bf16 h[2]; unsigned u; } x;
  x.h[0] = (bf16)a;
  x.h[1] = (bf16)b;
  return x.u;
}

// ---------------- causal GQA flash attention (swapped QK, 32x32 MFMA) ------
// Round-11/13/14/15-validated: 512 blocks, 4 waves, QBLK=128, complementary
// qt decode, conflict-free V LDS [c][d][8], s_setprio around MFMA clusters.
__global__ __launch_bounds__(256, 2) void k_attn(const bf16* __restrict__ qkv,
                                                 const bf16* __restrict__ Vt,
                                                 bf16* __restrict__ y) {
  int flat = blockIdx.x;
  int slot = flat >> 8;                 // 0 = heavy half, 1 = light half
  int j = flat & 255;
  int xcd = j & 7, iw = j >> 3;         // iw 0..31
  int h = xcd + 8 * (iw & 1);
  int r = iw >> 1;                      // 0..15
  int b = r & 1;
  int qt = slot ? (r >> 1) : (15 - (r >> 1));
  int kvh = h >> 2;
  int tid = threadIdx.x;
  int wid = tid >> 6, lane = tid & 63;
  int qc = lane & 31, hi = lane >> 5;
  __shared__ alignas(16) bf16 Ks[2][16 * 64 * 8];  // 2 x 16KB
  __shared__ alignas(16) bf16 Vs[2][8 * 128 * 8];  // 2 x 16KB, [c][d][8]
  const bf16* Qb = qkv + (size_t)(b * 2048) * 3072 + h * 128;
  const bf16* Kb = qkv + (size_t)(b * 2048) * 3072 + 2048 + kvh * 128;
  const bf16* Vb = Vt + (size_t)(b * 4 + kvh) * 262144;
  int qw0 = qt * 128 + wid * 32;
  int qg = qw0 + qc;
  bf16x8 qf[8];
#pragma unroll
  for (int s = 0; s < 8; ++s)
    qf[s] = *(const bf16x8*)&Qb[(size_t)qg * 3072 + s * 16 + hi * 8];
  f32x16 acc[4] = {};
  float mrun = -1e30f, lrun = 0.f;

  auto STAGE = [&](int buf, int kt2) {
    int s0 = kt2 * 64;
#pragma unroll
    for (int i = 0; i < 4; ++i) {  // K: slot = chunk*64+row
      int sl = i * 256 + tid;
      int ch = sl >> 6, row = sl & 63;
      LOAD_LDS16(Kb + (size_t)(s0 + row) * 3072 + ch * 8, &Ks[buf][sl * 8]);
    }
#pragma unroll
    for (int i = 0; i < 4; ++i) {  // V: linear from pre-permuted Vt
      int sl = i * 256 + tid;
      LOAD_LDS16(Vb + (size_t)kt2 * 8192 + sl * 8, &Vs[buf][sl * 8]);
    }
  };

  STAGE(0, 0);
  int cur = 0;
  int ktmax = 2 * qt + 1;
  for (int kt = 0; kt <= ktmax; ++kt) {
    int s0 = kt * 64;
    if (kt < ktmax) {
      STAGE(cur ^ 1, kt + 1);
      asm volatile("s_waitcnt vmcnt(8)" ::: "memory");
    } else {
      asm volatile("s_waitcnt vmcnt(0)" ::: "memory");
    }
    __builtin_amdgcn_s_barrier();
    __builtin_amdgcn_sched_barrier(0);
    if (s0 <= qw0 + 31) {
      f32x16 sc[2] = {};
      __builtin_amdgcn_s_setprio(1);
#pragma unroll
      for (int s = 0; s < 8; ++s)
#pragma unroll
        for (int n = 0; n < 2; ++n) {
          bf16x8 kf =
              *(const bf16x8*)&Ks[cur][(((2 * s + hi) << 6) + n * 32 + qc) * 8];
          sc[n] =
              __builtin_amdgcn_mfma_f32_32x32x16_bf16(kf, qf[s], sc[n], 0, 0, 0);
        }
      __builtin_amdgcn_s_setprio(0);
      if (s0 + 63 > qw0) {
#pragma unroll
        for (int n = 0; n < 2; ++n)
#pragma unroll
          for (int r2 = 0; r2 < 16; ++r2) {
            int kg = s0 + n * 32 + (r2 & 3) + 8 * (r2 >> 2) + 4 * hi;
            if (kg > qg) sc[n][r2] = -1e30f;
          }
      }
      float pm = -1e30f;
#pragma unroll
      for (int n = 0; n < 2; ++n)
#pragma unroll
        for (int r2 = 0; r2 < 16; ++r2) pm = fmaxf(pm, sc[n][r2]);
      pm = fmaxf(pm, __shfl_xor(pm, 32));
      if (__any(pm > mrun + 11.0f)) {
        float mnew = fmaxf(mrun, pm);
        float scl = EXP2F(mrun - mnew);
        mrun = mnew;
        lrun *= scl;
        float sv[16];
#pragma unroll
        for (int r2 = 0; r2 < 16; ++r2)
          sv[r2] = __shfl(scl, (r2 & 3) + 8 * (r2 >> 2) + 4 * hi);
#pragma unroll
        for (int dt = 0; dt < 4; ++dt)
#pragma unroll
          for (int r2 = 0; r2 < 16; ++r2) acc[dt][r2] *= sv[r2];
      }
      float rs = 0.f;
#pragma unroll
      for (int n = 0; n < 2; ++n) {
        unsigned pk[8];
#pragma unroll
        for (int mm = 0; mm < 8; ++mm) {
          float e0 = EXP2F(sc[n][2 * mm] - mrun);
          float e1 = EXP2F(sc[n][2 * mm + 1] - mrun);
          rs += e0 + e1;
          pk[mm] = pack2bf(e0, e1);
        }
#pragma unroll
        for (int l2 = 0; l2 < 2; ++l2) {
          unsigned a0 = pk[4 * l2 + 0], b0 = pk[4 * l2 + 2];
          unsigned a1 = pk[4 * l2 + 1], b1 = pk[4 * l2 + 3];
          asm volatile("v_permlane32_swap_b32 %0, %1" : "+v"(a0), "+v"(b0));
          asm volatile("v_permlane32_swap_b32 %0, %1" : "+v"(a1), "+v"(b1));
          u32x4 w = {a0, a1, b0, b1};
          bf16x8 pf = __builtin_bit_cast(bf16x8, w);
          int c = 2 * (2 * n + l2) + hi;  // t-chunk index
          __builtin_amdgcn_s_setprio(1);
#pragma unroll
          for (int dt = 0; dt < 4; ++dt) {
            bf16x8 vf =
                *(const bf16x8*)&Vs[cur][((c << 7) + dt * 32 + qc) * 8];
            acc[dt] =
                __builtin_amdgcn_mfma_f32_32x32x16_bf16(pf, vf, acc[dt], 0, 0, 0);
          }
          __builtin_amdgcn_s_setprio(0);
        }
      }
      rs += __shfl_xor(rs, 32);
      lrun += rs;
    }
    __builtin_amdgcn_sched_barrier(0);
    __builtin_amdgcn_s_barrier();
    cur ^= 1;
  }
  float rlv = 1.0f / lrun;
  float rcl[16];
#pragma unroll
  for (int r2 = 0; r2 < 16; ++r2)
    rcl[r2] = __shfl(rlv, (r2 & 3) + 8 * (r2 >> 2) + 4 * hi);
#pragma unroll
  for (int dt = 0; dt < 4; ++dt)
#pragma unroll
    for (int r2 = 0; r2 < 16; ++r2) {
      int row = qw0 + (r2 & 3) + 8 * (r2 >> 2) + 4 * hi;
      float v = acc[dt][r2] * rcl[r2];
      y[(size_t)(b * 2048 + row) * 2048 + h * 128 + dt * 32 + qc] = (bf16)v;
    }
}

// ---------------- launcher ----------------
extern "C" void kernel_launch(void* const* d_in, const int* in_sizes, int n_in,
                              void* d_out, int out_size, void* d_ws,
                              size_t ws_size, hipStream_t stream) {
  const float* x = (const float*)d_in[0];
  const float* Wqkv = (const float*)d_in[1];
  const float* Wproj = (const float*)d_in[2];
  const float* qs = (const float*)d_in[3];
  const float* ks = (const float*)d_in[4];
  float* out = (float*)d_out;
  char* ws = (char*)d_ws;

  bf16* xb = (bf16*)(ws);
  bf16* Wqkvt = (bf16*)(ws + (size_t)(16u << 20));
  bf16* Wprojt = (bf16*)(ws + (size_t)(28u << 20));
  bf16* qkv = (bf16*)(ws + (size_t)(36u << 20));
  bf16* Vt = Wqkvt;  // reuse after Wqkvt consumed by G1
  bf16* y = xb;      // reuse after xb consumed by G1

  k_pre<<<5632, 256, 0, stream>>>(x, Wqkv, xb, Wqkvt);
  k_gemm256<bf16, 256><<<dim3(16, 16), 512, 0, stream>>>(
      xb, Wqkvt, qkv, 4096, 3072, 2048, Wproj, Wprojt);
  k_post<<<4608, 256, 0, stream>>>(qkv, qs, ks, Vt);
  k_attn<<<dim3(512, 1, 1), 256, 0, stream>>>(qkv, Vt, y);
  k_gemm256<float, 128><<<dim3(32, 8), 512, 0, stream>>>(
      y, Wprojt, out, 4096, 2048, 2048, nullptr, nullptr);
}

// Round 20
// 237.662 us; speedup vs baseline: 1.1503x; 1.0199x over previous
//
#include <hip/hip_runtime.h>

typedef __bf16 bf16;
typedef __bf16 bf16x8 __attribute__((ext_vector_type(8)));
typedef __bf16 bf16x4 __attribute__((ext_vector_type(4)));
typedef float f32x4 __attribute__((ext_vector_type(4)));
typedef float f32x16 __attribute__((ext_vector_type(16)));
typedef unsigned u32x4 __attribute__((ext_vector_type(4)));

#define EXP2F(x) __builtin_amdgcn_exp2f(x)

#define LOAD_LDS16(gp, lp)                                                     \
  __builtin_amdgcn_global_load_lds(                                            \
      (const __attribute__((address_space(1))) void*)(gp),                     \
      (__attribute__((address_space(3))) void*)(lp), 16, 0, 0)

// ---- merged pre-pass: x f32->bf16 cvt (16B stores) + Wqkv transpose -------
__global__ __launch_bounds__(256) void k_pre(const float* __restrict__ x,
                                             const float* __restrict__ Wqkv,
                                             bf16* __restrict__ xb,
                                             bf16* __restrict__ Wqkvt) {
  int bid = blockIdx.x, tid = threadIdx.x;
  if (bid < 4096) {
    int i = bid * 256 + tid;
    float4 v0 = ((const float4*)x)[2 * i];
    float4 v1 = ((const float4*)x)[2 * i + 1];
    bf16x8 o = {(bf16)v0.x, (bf16)v0.y, (bf16)v0.z, (bf16)v0.w,
                (bf16)v1.x, (bf16)v1.y, (bf16)v1.z, (bf16)v1.w};
    ((bf16x8*)xb)[i] = o;
    return;
  }
  __shared__ bf16 t[64 * 65];
  int f = bid - 4096;                 // 0..1535
  int c0 = (f % 48) * 64, r0 = (f / 48) * 64;
  const int C = 3072, R = 2048;
#pragma unroll
  for (int i = 0; i < 16; ++i) {
    int f2 = i * 256 + tid;
    int rl = f2 >> 6, cl = f2 & 63;
    t[rl * 65 + cl] = (bf16)Wqkv[(size_t)(r0 + rl) * C + c0 + cl];
  }
  __syncthreads();
#pragma unroll
  for (int i = 0; i < 4; ++i) {
    int idx = i * 256 + tid;          // 1024 vec4 writes
    int cl = idx >> 4, rl0 = (idx & 15) * 4;
    bf16x4 o = {t[(rl0 + 0) * 65 + cl], t[(rl0 + 1) * 65 + cl],
                t[(rl0 + 2) * 65 + cl], t[(rl0 + 3) * 65 + cl]};
    *(bf16x4*)&Wqkvt[(size_t)(c0 + cl) * R + r0 + rl0] = o;
  }
}

// ---- bf16 GEMM, BMx256 tile — round-7/11 validated schedule ----
// QKV launch (grid 256, ntiles 192): blocks >= ntiles run Wproj transpose.
template <typename OutT, int BM>
__global__ __launch_bounds__(512, 2) void k_gemm256(const bf16* __restrict__ A,
                                                    const bf16* __restrict__ Bt,
                                                    OutT* __restrict__ C,
                                                    int M, int N, int K,
                                                    const float* __restrict__ Wp,
                                                    bf16* __restrict__ Wpt) {
  constexpr int ASZ = 4 * BM * 8;
  constexpr int MREP = BM / 32;
  __shared__ alignas(16) bf16 As[2][2][ASZ];
  __shared__ alignas(16) bf16 Bs[2][2][4 * 256 * 8];
  int tid = threadIdx.x;
  int wid = tid >> 6, lane = tid & 63;
  int g = lane >> 4, lr = lane & 15;
  int wrow = (wid >> 2) * (BM / 2), wcol = (wid & 3) * 64;
  int gx = gridDim.x;
  int flat = blockIdx.y * gx + blockIdx.x;
  int ntiles = (M / BM) * (N / 256);
  if (flat >= ntiles) {
    bf16* t = (bf16*)&As[0][0][0];
    int b2 = flat - ntiles;           // 0..63
    for (int k = 0; k < 16; ++k) {
      int st = b2 * 16 + k;
      int c0 = (st & 31) * 64, r0 = (st >> 5) * 64;
#pragma unroll
      for (int i = 0; i < 8; ++i) {
        int f2 = i * 512 + tid;
        int rl = f2 >> 6, cl = f2 & 63;
        t[rl * 65 + cl] = (bf16)Wp[(size_t)(r0 + rl) * 2048 + c0 + cl];
      }
      __syncthreads();
#pragma unroll
      for (int i = 0; i < 2; ++i) {
        int idx = i * 512 + tid;
        int cl = idx >> 4, rl0 = (idx & 15) * 4;
        bf16x4 o = {t[(rl0 + 0) * 65 + cl], t[(rl0 + 1) * 65 + cl],
                    t[(rl0 + 2) * 65 + cl], t[(rl0 + 3) * 65 + cl]};
        *(bf16x4*)&Wpt[(size_t)(c0 + cl) * 2048 + r0 + rl0] = o;
      }
      __syncthreads();
    }
    return;
  }
  int cpx = ntiles >> 3;
  int f2 = (flat & 7) * cpx + (flat >> 3);
  int row0 = (f2 % gx) * BM, col0 = (f2 / gx) * 256;
  int NT = K >> 6;
  f32x4 acc[MREP][4] = {};

  auto stageA = [&](int buf, int kh, int kt) {
#pragma unroll
    for (int pass = 0; pass < BM / 128; ++pass) {
      int slot = pass * 512 + tid;
      int kseg, row;
      if constexpr (BM == 256) { kseg = slot >> 8; row = slot & 255; }
      else { kseg = slot >> 7; row = slot & 127; }
      LOAD_LDS16(A + (size_t)(row0 + row) * K + kt * 64 + kh * 32 + kseg * 8,
                 &As[buf][kh][slot * 8]);
    }
  };
  auto stageB = [&](int buf, int kh, int kt) {
#pragma unroll
    for (int pass = 0; pass < 2; ++pass) {
      int slot = pass * 512 + tid;
      int kseg = slot >> 8, row = slot & 255;
      LOAD_LDS16(Bt + (size_t)(col0 + row) * K + kt * 64 + kh * 32 + kseg * 8,
                 &Bs[buf][kh][slot * 8]);
    }
  };
  auto dsA = [&](int buf, int s, int mq, bf16x8* af) {
#pragma unroll
    for (int i = 0; i < 4; ++i)
      af[i] = *(const bf16x8*)&As[buf][s]
                  [(g * BM + wrow + (mq * 4 + i) * 16 + lr) * 8];
  };
  auto dsB = [&](int buf, int s, bf16x8* bfr) {
#pragma unroll
    for (int i = 0; i < 4; ++i)
      bfr[i] = *(const bf16x8*)&Bs[buf][s][((g << 8) + wcol + i * 16 + lr) * 8];
  };
  auto mfma16 = [&](int mq, bf16x8* af, bf16x8* bfr) {
    __builtin_amdgcn_s_setprio(1);
#pragma unroll
    for (int i = 0; i < 4; ++i)
#pragma unroll
      for (int n = 0; n < 4; ++n)
        acc[mq * 4 + i][n] = __builtin_amdgcn_mfma_f32_16x16x32_bf16(
            af[i], bfr[n], acc[mq * 4 + i][n], 0, 0, 0);
    __builtin_amdgcn_s_setprio(0);
  };

  stageA(0, 0, 0);
  stageB(0, 0, 0);
  stageA(0, 1, 0);
  stageB(0, 1, 0);
  if constexpr (BM == 256)
    asm volatile("s_waitcnt vmcnt(4)" ::: "memory");
  else
    asm volatile("s_waitcnt vmcnt(3)" ::: "memory");
  __builtin_amdgcn_s_barrier();

  for (int T = 0; T < NT; ++T) {
    int buf = T & 1, nbuf = buf ^ 1;
    bool more = (T + 1 < NT);
    bf16x8 af[4], bfr[4];
    if constexpr (BM == 256) {
      dsA(buf, 0, 0, af);
      dsB(buf, 0, bfr);
      if (more) stageA(nbuf, 0, T + 1);
      __builtin_amdgcn_s_barrier();
      mfma16(0, af, bfr);
      __builtin_amdgcn_s_barrier();
      dsA(buf, 0, 1, af);
      if (more) {
        stageB(nbuf, 0, T + 1);
        asm volatile("s_waitcnt vmcnt(4)" ::: "memory");
      } else {
        asm volatile("s_waitcnt vmcnt(0)" ::: "memory");
      }
      __builtin_amdgcn_s_barrier();
      mfma16(1, af, bfr);
      __builtin_amdgcn_s_barrier();
      dsA(buf, 1, 0, af);
      dsB(buf, 1, bfr);
      if (more) stageA(nbuf, 1, T + 1);
      __builtin_amdgcn_s_barrier();
      mfma16(0, af, bfr);
      __builtin_amdgcn_s_barrier();
      dsA(buf, 1, 1, af);
      if (more) {
        stageB(nbuf, 1, T + 1);
        asm volatile("s_waitcnt vmcnt(4)" ::: "memory");
      }
      __builtin_amdgcn_s_barrier();
      mfma16(1, af, bfr);
      __builtin_amdgcn_s_barrier();
    } else {
      dsA(buf, 0, 0, af);
      dsB(buf, 0, bfr);
      if (more) {
        stageA(nbuf, 0, T + 1);
        stageB(nbuf, 0, T + 1);
        asm volatile("s_waitcnt vmcnt(3)" ::: "memory");
      } else {
        asm volatile("s_waitcnt vmcnt(0)" ::: "memory");
      }
      __builtin_amdgcn_s_barrier();
      mfma16(0, af, bfr);
      __builtin_amdgcn_s_barrier();
      dsA(buf, 1, 0, af);
      dsB(buf, 1, bfr);
      if (more) {
        stageA(nbuf, 1, T + 1);
        stageB(nbuf, 1, T + 1);
        asm volatile("s_waitcnt vmcnt(3)" ::: "memory");
      }
      __builtin_amdgcn_s_barrier();
      mfma16(0, af, bfr);
      __builtin_amdgcn_s_barrier();
    }
  }

#pragma unroll
  for (int mi = 0; mi < MREP; ++mi)
#pragma unroll
    for (int ni = 0; ni < 4; ++ni) {
      int rb = row0 + wrow + mi * 16 + g * 4;
      int cc = col0 + wcol + ni * 16 + lr;
#pragma unroll
      for (int r = 0; r < 4; ++r) C[(size_t)(rb + r) * N + cc] = (OutT)acc[mi][ni][r];
    }
}

// ---- post-pass: K RMS-norm (blocks 0..1023, 4 tokens/block) + V permute
// (blocks 1024..1535). Q-norm moved into k_attn's register prologue.
__global__ __launch_bounds__(256) void k_post(bf16* __restrict__ qkv,
                                              const float* __restrict__ ks,
                                              bf16* __restrict__ Vt) {
  int bid = blockIdx.x, tid = threadIdx.x;
  if (bid < 1024) {
    int wid = tid >> 6, lane = tid & 63;
    int tok = bid * 4 + wid;
    int d = lane * 2;
    bf16* rowp = qkv + (size_t)tok * 3072 + 2048;
#pragma unroll
    for (int kvh = 0; kvh < 4; ++kvh) {
      int cb = kvh * 128;
      float v0 = (float)rowp[cb + d], v1 = (float)rowp[cb + d + 1];
      float ss = v0 * v0 + v1 * v1;
#pragma unroll
      for (int off = 1; off < 64; off <<= 1) ss += __shfl_xor(ss, off);
      float r = rsqrtf(ss * (1.0f / 128.0f) + 1e-6f);
      rowp[cb + d] = (bf16)(v0 * r * ks[d]);
      rowp[cb + d + 1] = (bf16)(v1 * r * ks[d + 1]);
    }
    return;
  }
  // V transpose -> Vt[bh][kt(32)][c(8)][d(128)][8]
  __shared__ bf16 t[64 * 65];
  int f = bid - 1024;           // 0..511
  int t0 = (f & 31) * 64;
  int d0 = ((f >> 5) & 1) * 64;
  int bh = f >> 6;
  int b = bh >> 2, kvh = bh & 3;
  const bf16* src = qkv + (size_t)(b * 2048) * 3072 + 2560 + kvh * 128;
  bf16* dst = Vt + (size_t)bh * 262144 + (size_t)(t0 >> 6) * 8192;
#pragma unroll
  for (int i = 0; i < 16; ++i) {
    int ff = i * 256 + tid;
    int tl = ff >> 6, dl = ff & 63;
    t[tl * 65 + dl] = src[(size_t)(t0 + tl) * 3072 + d0 + dl];
  }
  __syncthreads();
#pragma unroll
  for (int i = 0; i < 2; ++i) {
    int v = i * 256 + tid;
    int c = v >> 6, dv = v & 63;
    bf16x8 o;
#pragma unroll
    for (int j = 0; j < 8; ++j) o[j] = t[(c * 8 + j) * 65 + dv];
    *(bf16x8*)&dst[(size_t)c * 1024 + (size_t)(d0 + dv) * 8] = o;
  }
}

__device__ inline unsigned pack2bf(float a, float b) {
  union { bf16 h[2]; unsigned u; } x;
  x.h[0] = (bf16)a;
  x.h[1] = (bf16)b;
  return x.u;
}

// ---------------- causal GQA flash attention (swapped QK, 32x32 MFMA) ------
// Round-11..19-validated loop. NEW: Q RMS-norm folded into register prologue
// (lane holds 64 of its q-row's 128 values; partner lane +-32 has the rest).
__global__ __launch_bounds__(256, 2) void k_attn(const bf16* __restrict__ qkv,
                                                 const bf16* __restrict__ Vt,
                                                 bf16* __restrict__ y,
                                                 const float* __restrict__ qs) {
  int flat = blockIdx.x;
  int slot = flat >> 8;                 // 0 = heavy half, 1 = light half
  int j = flat & 255;
  int xcd = j & 7, iw = j >> 3;         // iw 0..31
  int h = xcd + 8 * (iw & 1);
  int r = iw >> 1;                      // 0..15
  int b = r & 1;
  int qt = slot ? (r >> 1) : (15 - (r >> 1));
  int kvh = h >> 2;
  int tid = threadIdx.x;
  int wid = tid >> 6, lane = tid & 63;
  int qc = lane & 31, hi = lane >> 5;
  __shared__ alignas(16) bf16 Ks[2][16 * 64 * 8];  // 2 x 16KB
  __shared__ alignas(16) bf16 Vs[2][8 * 128 * 8];  // 2 x 16KB, [c][d][8]
  __shared__ float sqs[128];
  const bf16* Qb = qkv + (size_t)(b * 2048) * 3072 + h * 128;
  const bf16* Kb = qkv + (size_t)(b * 2048) * 3072 + 2048 + kvh * 128;
  const bf16* Vb = Vt + (size_t)(b * 4 + kvh) * 262144;
  int qw0 = qt * 128 + wid * 32;
  int qg = qw0 + qc;
  // scaled q-scale table (rsqrt(128)*log2e folded)
  if (tid < 128)
    sqs[tid] = qs[tid] * (0.08838834764831845f * 1.4426950408889634f);
  __syncthreads();
  bf16x8 qf[8];
#pragma unroll
  for (int s = 0; s < 8; ++s)
    qf[s] = *(const bf16x8*)&Qb[(size_t)qg * 3072 + s * 16 + hi * 8];
  // in-register Q RMS-norm: lane's 64 vals + partner's 64 via one shfl
  float ssq = 0.f;
#pragma unroll
  for (int s = 0; s < 8; ++s)
#pragma unroll
    for (int jj = 0; jj < 8; ++jj) {
      float v = (float)qf[s][jj];
      ssq += v * v;
    }
  ssq += __shfl_xor(ssq, 32);
  float qrms = rsqrtf(ssq * (1.0f / 128.0f) + 1e-6f);
#pragma unroll
  for (int s = 0; s < 8; ++s)
#pragma unroll
    for (int jj = 0; jj < 8; ++jj)
      qf[s][jj] = (bf16)((float)qf[s][jj] * qrms * sqs[s * 16 + hi * 8 + jj]);
  f32x16 acc[4] = {};
  float mrun = -1e30f, lrun = 0.f;

  auto STAGE = [&](int buf, int kt2) {
    int s0 = kt2 * 64;
#pragma unroll
    for (int i = 0; i < 4; ++i) {  // K: slot = chunk*64+row
      int sl = i * 256 + tid;
      int ch = sl >> 6, row = sl & 63;
      LOAD_LDS16(Kb + (size_t)(s0 + row) * 3072 + ch * 8, &Ks[buf][sl * 8]);
    }
#pragma unroll
    for (int i = 0; i < 4; ++i) {  // V: linear from pre-permuted Vt
      int sl = i * 256 + tid;
      LOAD_LDS16(Vb + (size_t)kt2 * 8192 + sl * 8, &Vs[buf][sl * 8]);
    }
  };

  STAGE(0, 0);
  int cur = 0;
  int ktmax = 2 * qt + 1;
  for (int kt = 0; kt <= ktmax; ++kt) {
    int s0 = kt * 64;
    if (kt < ktmax) {
      STAGE(cur ^ 1, kt + 1);
      asm volatile("s_waitcnt vmcnt(8)" ::: "memory");
    } else {
      asm volatile("s_waitcnt vmcnt(0)" ::: "memory");
    }
    __builtin_amdgcn_s_barrier();
    __builtin_amdgcn_sched_barrier(0);
    if (s0 <= qw0 + 31) {
      f32x16 sc[2] = {};
      __builtin_amdgcn_s_setprio(1);
#pragma unroll
      for (int s = 0; s < 8; ++s)
#pragma unroll
        for (int n = 0; n < 2; ++n) {
          bf16x8 kf =
              *(const bf16x8*)&Ks[cur][(((2 * s + hi) << 6) + n * 32 + qc) * 8];
          sc[n] =
              __builtin_amdgcn_mfma_f32_32x32x16_bf16(kf, qf[s], sc[n], 0, 0, 0);
        }
      __builtin_amdgcn_s_setprio(0);
      if (s0 + 63 > qw0) {
#pragma unroll
        for (int n = 0; n < 2; ++n)
#pragma unroll
          for (int r2 = 0; r2 < 16; ++r2) {
            int kg = s0 + n * 32 + (r2 & 3) + 8 * (r2 >> 2) + 4 * hi;
            if (kg > qg) sc[n][r2] = -1e30f;
          }
      }
      float pm = -1e30f;
#pragma unroll
      for (int n = 0; n < 2; ++n)
#pragma unroll
        for (int r2 = 0; r2 < 16; ++r2) pm = fmaxf(pm, sc[n][r2]);
      pm = fmaxf(pm, __shfl_xor(pm, 32));
      if (__any(pm > mrun + 11.0f)) {
        float mnew = fmaxf(mrun, pm);
        float scl = EXP2F(mrun - mnew);
        mrun = mnew;
        lrun *= scl;
        float sv[16];
#pragma unroll
        for (int r2 = 0; r2 < 16; ++r2)
          sv[r2] = __shfl(scl, (r2 & 3) + 8 * (r2 >> 2) + 4 * hi);
#pragma unroll
        for (int dt = 0; dt < 4; ++dt)
#pragma unroll
          for (int r2 = 0; r2 < 16; ++r2) acc[dt][r2] *= sv[r2];
      }
      float rs = 0.f;
#pragma unroll
      for (int n = 0; n < 2; ++n) {
        unsigned pk[8];
#pragma unroll
        for (int mm = 0; mm < 8; ++mm) {
          float e0 = EXP2F(sc[n][2 * mm] - mrun);
          float e1 = EXP2F(sc[n][2 * mm + 1] - mrun);
          rs += e0 + e1;
          pk[mm] = pack2bf(e0, e1);
        }
#pragma unroll
        for (int l2 = 0; l2 < 2; ++l2) {
          unsigned a0 = pk[4 * l2 + 0], b0 = pk[4 * l2 + 2];
          unsigned a1 = pk[4 * l2 + 1], b1 = pk[4 * l2 + 3];
          asm volatile("v_permlane32_swap_b32 %0, %1" : "+v"(a0), "+v"(b0));
          asm volatile("v_permlane32_swap_b32 %0, %1" : "+v"(a1), "+v"(b1));
          u32x4 w = {a0, a1, b0, b1};
          bf16x8 pf = __builtin_bit_cast(bf16x8, w);
          int c = 2 * (2 * n + l2) + hi;  // t-chunk index
          __builtin_amdgcn_s_setprio(1);
#pragma unroll
          for (int dt = 0; dt < 4; ++dt) {
            bf16x8 vf =
                *(const bf16x8*)&Vs[cur][((c << 7) + dt * 32 + qc) * 8];
            acc[dt] =
                __builtin_amdgcn_mfma_f32_32x32x16_bf16(pf, vf, acc[dt], 0, 0, 0);
          }
          __builtin_amdgcn_s_setprio(0);
        }
      }
      rs += __shfl_xor(rs, 32);
      lrun += rs;
    }
    __builtin_amdgcn_sched_barrier(0);
    __builtin_amdgcn_s_barrier();
    cur ^= 1;
  }
  float rlv = 1.0f / lrun;
  float rcl[16];
#pragma unroll
  for (int r2 = 0; r2 < 16; ++r2)
    rcl[r2] = __shfl(rlv, (r2 & 3) + 8 * (r2 >> 2) + 4 * hi);
#pragma unroll
  for (int dt = 0; dt < 4; ++dt)
#pragma unroll
    for (int r2 = 0; r2 < 16; ++r2) {
      int row = qw0 + (r2 & 3) + 8 * (r2 >> 2) + 4 * hi;
      float v = acc[dt][r2] * rcl[r2];
      y[(size_t)(b * 2048 + row) * 2048 + h * 128 + dt * 32 + qc] = (bf16)v;
    }
}

// ---------------- launcher ----------------
extern "C" void kernel_launch(void* const* d_in, const int* in_sizes, int n_in,
                              void* d_out, int out_size, void* d_ws,
                              size_t ws_size, hipStream_t stream) {
  const float* x = (const float*)d_in[0];
  const float* Wqkv = (const float*)d_in[1];
  const float* Wproj = (const float*)d_in[2];
  const float* qs = (const float*)d_in[3];
  const float* ks = (const float*)d_in[4];
  float* out = (float*)d_out;
  char* ws = (char*)d_ws;

  bf16* xb = (bf16*)(ws);
  bf16* Wqkvt = (bf16*)(ws + (size_t)(16u << 20));
  bf16* Wprojt = (bf16*)(ws + (size_t)(28u << 20));
  bf16* qkv = (bf16*)(ws + (size_t)(36u << 20));
  bf16* Vt = Wqkvt;  // reuse after Wqkvt consumed by G1
  bf16* y = xb;      // reuse after xb consumed by G1

  k_pre<<<5632, 256, 0, stream>>>(x, Wqkv, xb, Wqkvt);
  k_gemm256<bf16, 256><<<dim3(16, 16), 512, 0, stream>>>(
      xb, Wqkvt, qkv, 4096, 3072, 2048, Wproj, Wprojt);
  k_post<<<1536, 256, 0, stream>>>(qkv, ks, Vt);
  k_attn<<<dim3(512, 1, 1), 256, 0, stream>>>(qkv, Vt, y, qs);
  k_gemm256<float, 128><<<dim3(32, 8), 512, 0, stream>>>(
      y, Wprojt, out, 4096, 2048, 2048, nullptr, nullptr);
}